// Round 13
// baseline (546.695 us; speedup 1.0000x reference)
//
#include <hip/hip_runtime.h>
#include <hip/hip_bf16.h>
#include <stdint.h>

#define AS1 __attribute__((address_space(1)))
#define AS3 __attribute__((address_space(3)))

typedef __attribute__((ext_vector_type(8))) short short8v;
typedef __attribute__((ext_vector_type(4))) float float4v;

#define NT 64
#define CCH 256
#define HH 56
#define WW 56
#define HWSZ 3136
#define HP 58
#define WP 58

// workspace layout (bytes)
#define OFF_XT   0ull
#define SZ_XT    110231552ull          // 64*58*58*256*2  (bf16 NHWC padded)
#define OFF_WPK  (OFF_XT + SZ_XT)
#define SZ_WPK   1179648ull            // 9*256*256*2
#define OFF_CS   (OFF_WPK + SZ_WPK)
#define SZ_CS    65536ull              // 64*256 f32 channel sums
#define OFF_XG2  (OFF_CS + SZ_CS)
#define SZ_XG2   8192ull               // 8*256 f32
#define OFF_WGT  (OFF_XG2 + SZ_XG2)
#define SZ_WGT   24576ull              // 8*256*3 f32
#define OFF_M    (OFF_WGT + SZ_WGT)
#define SZ_M     65536ull              // 8*256*8 f32
#define OFF_GATE (OFF_M + SZ_M)
#define SZ_GATE  65536ull              // 64*256 f32

__device__ __forceinline__ unsigned short f2bf(float f) {
    unsigned int u = __float_as_uint(f);
    unsigned int r = (u + 0x7fffu + ((u >> 16) & 1u)) >> 16;
    return (unsigned short)r;
}

__device__ __forceinline__ void gload16(const unsigned short* g, unsigned short* l) {
    __builtin_amdgcn_global_load_lds((const AS1 void*)g, (AS3 void*)l, 16, 0, 0);
}

// ---------------- K0: NCHW f32 -> NHWC-padded bf16 (with zero borders) ----
__global__ __launch_bounds__(256) void k0_transpose(const float* __restrict__ x,
                                                    unsigned short* __restrict__ xt) {
    int b = blockIdx.x;              // (nt, h, cb) : 64*56*4
    int cb = b & 3;
    int h  = (b >> 2) % 56;
    int nt = b / (4 * 56);
    int c0 = cb * 64;
    int tid = threadIdx.x;

    __shared__ float xs[64 * 57];    // padded stride 57 to dodge bank conflicts

    const float* src = x + ((size_t)nt * CCH + c0) * HWSZ + h * WW;
    for (int li = tid; li < 896; li += 256) {       // 64 rows * 14 float4
        int row = li / 14, f4 = li % 14;
        float4v v = *(const float4v*)(src + (size_t)row * HWSZ + f4 * 4);
        float* d = &xs[row * 57 + f4 * 4];
        d[0] = v.x; d[1] = v.y; d[2] = v.z; d[3] = v.w;
    }
    __syncthreads();

    unsigned short* dst = xt + (((size_t)nt * HP + (h + 1)) * WP) * CCH + c0;
    for (int job = tid; job < 464; job += 256) {    // 58 ww * 8 cgroups
        int ww = job >> 3, cg = job & 7;
        short8v v;
        if (ww == 0 || ww == 57) {
            v = (short8v){0,0,0,0,0,0,0,0};
        } else {
            #pragma unroll
            for (int jj = 0; jj < 8; ++jj)
                v[jj] = (short)f2bf(xs[(cg * 8 + jj) * 57 + (ww - 1)]);
        }
        *(short8v*)(dst + ww * CCH + cg * 8) = v;
    }
    if (h == 0) {   // zero rows hh=0 and hh=57
        unsigned short* d0  = xt + ((size_t)nt * HP + 0)  * WP * CCH + c0;
        unsigned short* d57 = xt + ((size_t)nt * HP + 57) * WP * CCH + c0;
        short8v z = (short8v){0,0,0,0,0,0,0,0};
        for (int job = tid; job < 464; job += 256) {
            int ww = job >> 3, cg = job & 7;
            *(short8v*)(d0  + ww * CCH + cg * 8) = z;
            *(short8v*)(d57 + ww * CCH + cg * 8) = z;
        }
    }
}

// ---------------- KW: pack conv weights -> [rs][k][c] bf16 ----------------
__global__ __launch_bounds__(256) void kw_pack(const float* __restrict__ nw,
                                               unsigned short* __restrict__ wpk) {
    int idx = blockIdx.x * 256 + threadIdx.x;       // 9*256*256 = 589824
    int rs = idx >> 16;
    int k  = (idx >> 8) & 255;
    int c  = idx & 255;
    wpk[idx] = f2bf(nw[(k * 256 + c) * 9 + rs]);
}

// ---------------- KI: init tail-tile region (bias) + csum bias terms ------
// Tail tiles = pixel range [196608, 200704) (32 tiles of 128 px).  These are
// computed via split-K atomicAdd by conv blocks; out must start at bias and
// chansum must get the bias part (64*bias per 64-px chunk, indexed by image).
__global__ __launch_bounds__(256) void kinit(const float* __restrict__ net_b,
                                             float* __restrict__ out,
                                             float* __restrict__ chansum) {
    int idx = blockIdx.x * 256 + threadIdx.x;    // 4096 blocks -> 1,048,576
    int m  = idx >> 12;          // 0..255
    int pp = idx & 4095;         // 0..4095
    int p  = 196608 + pp;
    int nt = p / HWSZ, hw = p - nt * HWSZ;
    out[((size_t)nt * CCH + m) * HWSZ + hw] = net_b[m];
    if (pp < 64) {               // 64 chunks of 64 px
        int pc = 196608 + pp * 64;
        int img = pc / HWSZ;
        atomicAdd(&chansum[img * CCH + m], 64.0f * net_b[m]);
    }
}

// ---------------- conv: implicit GEMM, 256x128x32, split-K tail -----------
// R13 = R11 inner structure (best: 296us, in-block util ~46%) + TAIL FIX v2.
// R11's 1568 tiles / 512 slots = 3.0625 -> makespan 4 rounds (23% idle; the
// fold couldn't help: capacity at 3T = 1536 < 1568, last 32 units atomic).
// Fix: grid = 512 blocks exactly (2/CU, ALL co-resident, no queuing).  Each
// block: 3 full tiles (g = pb0, +512, +1024 -> tiles 0..1535) + one K-SLICE
// (4 or 5 of 72 k-tiles) of tail tile (pb0>>4); 16 slices x 32 tiles = 512.
// Slices accumulate via f32 atomicAdd (no bias; kinit pre-writes bias).
// Every block's work = 3.065 tile-times -> balanced makespan ~3.07T vs 4T.

#define STGALL(bi_, tA_, tB_) do { \
    gload16(wpk + (tA_) + aoffg0, &lds[(bi_) * 8192 + ldsa0]); \
    gload16(wpk + (tA_) + aoffg1, &lds[(bi_) * 8192 + ldsa1]); \
    gload16(xt  + (tB_) + boffg,  &lds[24576 + (bi_) * 4096 + ldsb]); \
} while (0)

#define LDAF(mi) (*(const short8v*)&lds[abase + (wm * 64 + (mi) * 16 + r16) * 32 + pA * 8])
#define LDBF(j)  (*(const short8v*)&lds[bbase + (wp * 64 + (j) * 16 + r16) * 32 + pA * 8])

#define KTA(kt) ((((kt) >> 3) << 16) + (((kt) & 7) * 32))
#define KTB(kt) (((((kt) >> 3) / 3) * WP + (((kt) >> 3) - (((kt) >> 3) / 3) * 3)) * 256 + (((kt) & 7) * 32))

#define BARSYNC do { \
    __builtin_amdgcn_s_barrier(); \
    __builtin_amdgcn_sched_barrier(0); \
} while (0)

__global__ __launch_bounds__(512, 4) void conv_mfma(const unsigned short* __restrict__ xt,
                                                    const unsigned short* __restrict__ wpk,
                                                    const float* __restrict__ net_b,
                                                    float* __restrict__ out,
                                                    float* __restrict__ chansum) {
    __shared__ unsigned short lds[36864];  // 72 KB: A ring 3x8192, B ring 3x4096

    const int tid  = threadIdx.x;
    const int lane = tid & 63;
    const int wid  = tid >> 6;         // 0..7
    const int wm   = wid >> 1;         // 0..3  (m quarter, 64 rows)
    const int wp   = wid & 1;          // 0..1  (pixel half, 64 px)
    const int r16  = lane & 15;
    const int hi   = lane >> 4;        // 0..3  (k-chunk)
    const int pA   = (hi + (r16 >> 1)) & 3;   // rotation-swizzle read position

    // XCD-aware bijective swizzle: 512 = 8 * 64
    const int pb0 = (blockIdx.x & 7) * 64 + (blockIdx.x >> 3);

    // A staging precompute: slot s -> row r = s>>2, pos p = s&3 holds global
    // chunk cg = (p - (r>>1)) & 3; 4 lanes/row -> 64 B contiguous.
    const int cgs = ((tid & 3) - (tid >> 3)) & 3;
    const int aoffg0 = (tid >> 2) * 256 + cgs * 8;   // A rows 0..127
    const int aoffg1 = aoffg0 + 32768;               // A rows 128..255
    const int ldsa0  = tid * 8;
    const int ldsa1  = ldsa0 + 4096;
    const int ldsb   = tid * 8;

    // ================= 3 full tiles =================
    for (int gi = 0; gi < 3; ++gi) {
        const int g = pb0 + gi * 512;
        const int p0 = g * 128;

        long boffg;
        {
            int r = tid >> 2;              // pixel row 0..127
            int p = p0 + r;
            int nt = p / HWSZ, hw = p - nt * HWSZ;
            int hh = hw / WW,  w  = hw - hh * WW;
            boffg = ((long)(nt * HP + hh) * WP + w) * 256 + cgs * 8;
        }

        float4v acc[4][4];
        #pragma unroll
        for (int i = 0; i < 4; ++i)
            #pragma unroll
            for (int j = 0; j < 4; ++j) acc[i][j] = (float4v){0.f, 0.f, 0.f, 0.f};

        // prologue: stage tiles 0,1 into ring slots 0,1
        STGALL(0, 0, 0);
        STGALL(1, 32, 32);

        int cur = 0;
        for (int kt = 0; kt < 72; ++kt) {
            const int abase = cur * 8192;
            const int bbase = 24576 + cur * 4096;

            if (kt < 70) {
                const int ktn = kt + 2;
                int nb2 = cur + 2; if (nb2 >= 3) nb2 -= 3;
                STGALL(nb2, KTA(ktn), KTB(ktn));
                asm volatile("s_waitcnt vmcnt(6)" ::: "memory");
            } else if (kt == 70) {
                asm volatile("s_waitcnt vmcnt(3)" ::: "memory");
            } else {
                asm volatile("s_waitcnt vmcnt(0)" ::: "memory");
            }
            BARSYNC;                       // tile kt sealed for all waves

            short8v afrag[4], bfrag[4];
            #pragma unroll
            for (int mi = 0; mi < 4; ++mi) afrag[mi] = LDAF(mi);
            #pragma unroll
            for (int j = 0; j < 4; ++j) bfrag[j] = LDBF(j);

            asm volatile("s_waitcnt lgkmcnt(0)" ::: "memory");
            __builtin_amdgcn_sched_barrier(0);
            __builtin_amdgcn_s_setprio(1);
            #pragma unroll
            for (int j = 0; j < 4; ++j)
                #pragma unroll
                for (int mi = 0; mi < 4; ++mi)
                    acc[mi][j] = __builtin_amdgcn_mfma_f32_16x16x32_bf16(afrag[mi], bfrag[j], acc[mi][j], 0, 0, 0);
            __builtin_amdgcn_s_setprio(0);
            BARSYNC;                       // WAR: buffer cur free for restage

            ++cur; if (cur >= 3) cur = 0;
        }

        // epilogue: bias + store + fused channel-sum
        const int pw = p0 + wp * 64;   // 64-aligned -> whole wave-chunk same image
        const int ntw = pw / HWSZ;
        const int hwb = pw - ntw * HWSZ;
        #pragma unroll
        for (int mi = 0; mi < 4; ++mi) {
            #pragma unroll
            for (int r = 0; r < 4; ++r) {
                const int m = wm * 64 + mi * 16 + hi * 4 + r;
                const float bias = net_b[m];
                float csum = 0.f;
                float* orow = out + ((size_t)ntw * CCH + m) * HWSZ + hwb;
                #pragma unroll
                for (int j = 0; j < 4; ++j) {
                    float v = acc[mi][j][r] + bias;
                    orow[j * 16 + r16] = v;
                    csum += v;
                }
                csum += __shfl_xor(csum, 1);
                csum += __shfl_xor(csum, 2);
                csum += __shfl_xor(csum, 4);
                csum += __shfl_xor(csum, 8);
                if (r16 == 0) atomicAdd(&chansum[ntw * CCH + m], csum);
            }
        }
    }

    // ================= split-K tail slice =================
    {
        const int tt  = pb0 >> 4;                  // tail tile 0..31
        const int p0  = (1536 + tt) * 128;
        const int ks  = pb0 & 15;                  // slice 0..15
        const int k0  = (ks < 8) ? ks * 5 : 40 + (ks - 8) * 4;
        const int klen = (ks < 8) ? 5 : 4;

        long boffg;
        {
            int r = tid >> 2;
            int p = p0 + r;
            int nt = p / HWSZ, hw = p - nt * HWSZ;
            int hh = hw / WW,  w  = hw - hh * WW;
            boffg = ((long)(nt * HP + hh) * WP + w) * 256 + cgs * 8;
        }

        float4v acc[4][4];
        #pragma unroll
        for (int i = 0; i < 4; ++i)
            #pragma unroll
            for (int j = 0; j < 4; ++j) acc[i][j] = (float4v){0.f, 0.f, 0.f, 0.f};

        STGALL(0, KTA(k0), KTB(k0));
        STGALL(1, KTA(k0 + 1), KTB(k0 + 1));

        int cur = 0;
        for (int i = 0; i < klen; ++i) {
            const int abase = cur * 8192;
            const int bbase = 24576 + cur * 4096;
            if (i + 2 < klen) {
                int s2 = cur + 2; if (s2 >= 3) s2 -= 3;
                const int ktn = k0 + i + 2;
                STGALL(s2, KTA(ktn), KTB(ktn));
                asm volatile("s_waitcnt vmcnt(6)" ::: "memory");
            } else if (i + 1 < klen) {
                asm volatile("s_waitcnt vmcnt(3)" ::: "memory");
            } else {
                asm volatile("s_waitcnt vmcnt(0)" ::: "memory");
            }
            BARSYNC;

            short8v afrag[4], bfrag[4];
            #pragma unroll
            for (int mi = 0; mi < 4; ++mi) afrag[mi] = LDAF(mi);
            #pragma unroll
            for (int j = 0; j < 4; ++j) bfrag[j] = LDBF(j);

            asm volatile("s_waitcnt lgkmcnt(0)" ::: "memory");
            __builtin_amdgcn_sched_barrier(0);
            __builtin_amdgcn_s_setprio(1);
            #pragma unroll
            for (int j = 0; j < 4; ++j)
                #pragma unroll
                for (int mi = 0; mi < 4; ++mi)
                    acc[mi][j] = __builtin_amdgcn_mfma_f32_16x16x32_bf16(afrag[mi], bfrag[j], acc[mi][j], 0, 0, 0);
            __builtin_amdgcn_s_setprio(0);
            BARSYNC;

            ++cur; if (cur >= 3) cur = 0;
        }

        // slice epilogue: atomic accumulate (no bias), atomic partial csum
        const int pw = p0 + wp * 64;
        const int ntw = pw / HWSZ;
        const int hwb = pw - ntw * HWSZ;
        #pragma unroll
        for (int mi = 0; mi < 4; ++mi) {
            #pragma unroll
            for (int r = 0; r < 4; ++r) {
                const int m = wm * 64 + mi * 16 + hi * 4 + r;
                float csum = 0.f;
                float* orow = out + ((size_t)ntw * CCH + m) * HWSZ + hwb;
                #pragma unroll
                for (int j = 0; j < 4; ++j) {
                    float v = acc[mi][j][r];
                    atomicAdd(&orow[j * 16 + r16], v);
                    csum += v;
                }
                csum += __shfl_xor(csum, 1);
                csum += __shfl_xor(csum, 2);
                csum += __shfl_xor(csum, 4);
                csum += __shfl_xor(csum, 8);
                if (r16 == 0) atomicAdd(&chansum[ntw * CCH + m], csum);
            }
        }
    }
}

// ---------------- K2: x_g -> lam 1x1 conv -> xg2[n][c] --------------------
__global__ __launch_bounds__(256) void k2_xg(const float* __restrict__ chansum,
                                             const float* __restrict__ lam_w,
                                             const float* __restrict__ lam_b,
                                             float* __restrict__ xg2) {
    int n = blockIdx.x, c = threadIdx.x;
    __shared__ float xs[256];
    float s = 0.f;
    #pragma unroll
    for (int t = 0; t < 8; ++t) s += chansum[(n * 8 + t) * CCH + c];
    xs[c] = s * (1.0f / (3136.f * 8.f));
    __syncthreads();
    float d = lam_b[c];
    const float* row = lam_w + c * 256;
    for (int cc = 0; cc < 256; ++cc) d += row[cc] * xs[cc];
    xg2[n * 256 + c] = d;
}

// ---------------- K3: MLP+BN+softmax weights, m[n][c][t] ------------------
__global__ __launch_bounds__(256) void k3_wgt(const float* __restrict__ chansum,
                                              const float* __restrict__ xg2,
                                              const float* __restrict__ w1,
                                              const float* __restrict__ bg,
                                              const float* __restrict__ bb,
                                              const float* __restrict__ bm,
                                              const float* __restrict__ bv,
                                              const float* __restrict__ w2,
                                              float* __restrict__ wgt,
                                              float* __restrict__ mbuf) {
    int idx = blockIdx.x * 256 + threadIdx.x;    // n*256+c, 2048
    int n = idx >> 8, c = idx & 255;
    float xg = xg2[idx];
    float p[8];
    #pragma unroll
    for (int t = 0; t < 8; ++t)
        p[t] = chansum[(n * 8 + t) * CCH + c] * (1.0f / 3136.f) + xg;
    float hd[16];
    #pragma unroll
    for (int j = 0; j < 16; ++j) {
        float s = 0.f;
        #pragma unroll
        for (int t = 0; t < 8; ++t) s += p[t] * w1[j * 8 + t];
        s = (s - bm[j]) * (bg[j] * rsqrtf(bv[j] + 1e-5f)) + bb[j];
        hd[j] = fmaxf(s, 0.f);
    }
    float lg[3];
    #pragma unroll
    for (int k = 0; k < 3; ++k) {
        float s = 0.f;
        #pragma unroll
        for (int j = 0; j < 16; ++j) s += hd[j] * w2[k * 16 + j];
        lg[k] = s;
    }
    float mx = fmaxf(fmaxf(lg[0], lg[1]), lg[2]);
    float e0 = expf(lg[0] - mx), e1 = expf(lg[1] - mx), e2 = expf(lg[2] - mx);
    float inv = 1.f / (e0 + e1 + e2);
    float wk[3] = {e0 * inv, e1 * inv, e2 * inv};
    #pragma unroll
    for (int k = 0; k < 3; ++k) wgt[idx * 3 + k] = wk[k];
    #pragma unroll
    for (int t = 0; t < 8; ++t) {
        float s = 0.f;
        #pragma unroll
        for (int k = 0; k < 3; ++k) {
            int tt = t + k - 1;
            if (tt >= 0 && tt < 8) s += wk[k] * p[tt];
        }
        mbuf[idx * 8 + t] = s;
    }
}

// ---------------- K4: ME gate[nt][c] --------------------------------------
__global__ __launch_bounds__(256) void k4_gate(const float* __restrict__ mbuf,
                                               const float* __restrict__ me_w,
                                               float* __restrict__ gate) {
    int b = blockIdx.x;          // n*8+t
    int n = b >> 3, t = b & 7;
    int c = threadIdx.x;
    __shared__ float y[256];
    float yv = 0.f;
    if (t < 7) yv = mbuf[(n * 256 + c) * 8 + t + 1] - mbuf[(n * 256 + c) * 8 + t];
    y[c] = yv;
    __syncthreads();
    float yc = me_w[1] * yv;
    if (c > 0)   yc += me_w[0] * y[c - 1];
    if (c < 255) yc += me_w[2] * y[c + 1];
    gate[b * 256 + c] = 1.f / (1.f + expf(-yc));
}

// ---------------- K5: temporal mix + gate, in-place on d_out --------------
__global__ __launch_bounds__(256) void k5_final(float* __restrict__ out,
                                                const float* __restrict__ wgt,
                                                const float* __restrict__ xg2,
                                                const float* __restrict__ gate) {
    int tid = blockIdx.x * 256 + threadIdx.x;   // 2048 * 784
    int hw4 = tid % 784;
    int nc = tid / 784;
    int n = nc >> 8, c = nc & 255;
    float w0 = wgt[nc * 3 + 0], w1 = wgt[nc * 3 + 1], w2 = wgt[nc * 3 + 2];
    float xg = xg2[nc];
    const size_t tstride = (size_t)CCH * HWSZ;
    size_t base = ((size_t)(n * 8) * CCH + c) * HWSZ + hw4 * 4;

    float4v o[8];
    #pragma unroll
    for (int t = 0; t < 8; ++t) o[t] = *(const float4v*)(out + base + t * tstride);

    #pragma unroll
    for (int t = 0; t < 8; ++t) {
        float g = gate[(n * 8 + t) * CCH + c];
        float4v lam;
        #pragma unroll
        for (int q = 0; q < 4; ++q) {
            float v = w1 * (o[t][q] + xg);
            if (t > 0) v += w0 * (o[t - 1][q] + xg);
            if (t < 7) v += w2 * (o[t + 1][q] + xg);
            lam[q] = g * v;
        }
        *(float4v*)(out + base + t * tstride) = lam;
    }
}

extern "C" void kernel_launch(void* const* d_in, const int* in_sizes, int n_in,
                              void* d_out, int out_size, void* d_ws, size_t ws_size,
                              hipStream_t stream) {
    const float* x      = (const float*)d_in[0];
    const float* net_w  = (const float*)d_in[1];
    const float* net_b  = (const float*)d_in[2];
    const float* lam_w  = (const float*)d_in[3];
    const float* lam_b  = (const float*)d_in[4];
    const float* mlp_w1 = (const float*)d_in[5];
    const float* bn_g   = (const float*)d_in[6];
    const float* bn_b   = (const float*)d_in[7];
    const float* bn_m   = (const float*)d_in[8];
    const float* bn_v   = (const float*)d_in[9];
    const float* mlp_w2 = (const float*)d_in[10];
    const float* me_w   = (const float*)d_in[11];
    float* out = (float*)d_out;

    char* ws = (char*)d_ws;
    unsigned short* xt  = (unsigned short*)(ws + OFF_XT);
    unsigned short* wpk = (unsigned short*)(ws + OFF_WPK);
    float* chansum = (float*)(ws + OFF_CS);
    float* xg2     = (float*)(ws + OFF_XG2);
    float* wgt     = (float*)(ws + OFF_WGT);
    float* mbuf    = (float*)(ws + OFF_M);
    float* gate    = (float*)(ws + OFF_GATE);

    hipMemsetAsync(chansum, 0, SZ_CS, stream);
    kw_pack<<<2304, 256, 0, stream>>>(net_w, wpk);
    kinit<<<4096, 256, 0, stream>>>(net_b, out, chansum);
    k0_transpose<<<64 * 56 * 4, 256, 0, stream>>>(x, xt);
    conv_mfma<<<512, 512, 0, stream>>>(xt, wpk, net_b, out, chansum);
    k2_xg<<<8, 256, 0, stream>>>(chansum, lam_w, lam_b, xg2);
    k3_wgt<<<8, 256, 0, stream>>>(chansum, xg2, mlp_w1, bn_g, bn_b, bn_m, bn_v, mlp_w2, wgt, mbuf);
    k4_gate<<<64, 256, 0, stream>>>(mbuf, me_w, gate);
    k5_final<<<6272, 256, 0, stream>>>(out, wgt, xg2, gate);
}

// Round 14
// 486.574 us; speedup vs baseline: 1.1236x; 1.1236x over previous
//
#include <hip/hip_runtime.h>
#include <hip/hip_bf16.h>
#include <stdint.h>

#define AS1 __attribute__((address_space(1)))
#define AS3 __attribute__((address_space(3)))

typedef __attribute__((ext_vector_type(8))) short short8v;
typedef __attribute__((ext_vector_type(4))) float float4v;
typedef __attribute__((ext_vector_type(16))) float float16v;

#define NT 64
#define CCH 256
#define HH 56
#define WW 56
#define HWSZ 3136
#define HP 58
#define WP 58

// workspace layout (bytes)
#define OFF_XT   0ull
#define SZ_XT    110231552ull          // 64*58*58*256*2  (bf16 NHWC padded)
#define OFF_WPK  (OFF_XT + SZ_XT)
#define SZ_WPK   1179648ull            // 9*256*256*2
#define OFF_CS   (OFF_WPK + SZ_WPK)
#define SZ_CS    65536ull              // 64*256 f32 channel sums
#define OFF_XG2  (OFF_CS + SZ_CS)
#define SZ_XG2   8192ull               // 8*256 f32
#define OFF_WGT  (OFF_XG2 + SZ_XG2)
#define SZ_WGT   24576ull              // 8*256*3 f32
#define OFF_M    (OFF_WGT + SZ_WGT)
#define SZ_M     65536ull              // 8*256*8 f32
#define OFF_GATE (OFF_M + SZ_M)
#define SZ_GATE  65536ull              // 64*256 f32

__device__ __forceinline__ unsigned short f2bf(float f) {
    unsigned int u = __float_as_uint(f);
    unsigned int r = (u + 0x7fffu + ((u >> 16) & 1u)) >> 16;
    return (unsigned short)r;
}

__device__ __forceinline__ void gload16(const unsigned short* g, unsigned short* l) {
    __builtin_amdgcn_global_load_lds((const AS1 void*)g, (AS3 void*)l, 16, 0, 0);
}

// ---------------- K0: NCHW f32 -> NHWC-padded bf16 (with zero borders) ----
__global__ __launch_bounds__(256) void k0_transpose(const float* __restrict__ x,
                                                    unsigned short* __restrict__ xt) {
    int b = blockIdx.x;              // (nt, h, cb) : 64*56*4
    int cb = b & 3;
    int h  = (b >> 2) % 56;
    int nt = b / (4 * 56);
    int c0 = cb * 64;
    int tid = threadIdx.x;

    __shared__ float xs[64 * 57];    // padded stride 57 to dodge bank conflicts

    const float* src = x + ((size_t)nt * CCH + c0) * HWSZ + h * WW;
    for (int li = tid; li < 896; li += 256) {       // 64 rows * 14 float4
        int row = li / 14, f4 = li % 14;
        float4v v = *(const float4v*)(src + (size_t)row * HWSZ + f4 * 4);
        float* d = &xs[row * 57 + f4 * 4];
        d[0] = v.x; d[1] = v.y; d[2] = v.z; d[3] = v.w;
    }
    __syncthreads();

    unsigned short* dst = xt + (((size_t)nt * HP + (h + 1)) * WP) * CCH + c0;
    for (int job = tid; job < 464; job += 256) {    // 58 ww * 8 cgroups
        int ww = job >> 3, cg = job & 7;
        short8v v;
        if (ww == 0 || ww == 57) {
            v = (short8v){0,0,0,0,0,0,0,0};
        } else {
            #pragma unroll
            for (int jj = 0; jj < 8; ++jj)
                v[jj] = (short)f2bf(xs[(cg * 8 + jj) * 57 + (ww - 1)]);
        }
        *(short8v*)(dst + ww * CCH + cg * 8) = v;
    }
    if (h == 0) {   // zero rows hh=0 and hh=57
        unsigned short* d0  = xt + ((size_t)nt * HP + 0)  * WP * CCH + c0;
        unsigned short* d57 = xt + ((size_t)nt * HP + 57) * WP * CCH + c0;
        short8v z = (short8v){0,0,0,0,0,0,0,0};
        for (int job = tid; job < 464; job += 256) {
            int ww = job >> 3, cg = job & 7;
            *(short8v*)(d0  + ww * CCH + cg * 8) = z;
            *(short8v*)(d57 + ww * CCH + cg * 8) = z;
        }
    }
}

// ---------------- KW: pack conv weights -> [rs][k][c] bf16 ----------------
__global__ __launch_bounds__(256) void kw_pack(const float* __restrict__ nw,
                                               unsigned short* __restrict__ wpk) {
    int idx = blockIdx.x * 256 + threadIdx.x;       // 9*256*256 = 589824
    int rs = idx >> 16;
    int k  = (idx >> 8) & 255;
    int c  = idx & 255;
    wpk[idx] = f2bf(nw[(k * 256 + c) * 9 + rs]);
}

// ---------------- conv: implicit GEMM, 256x128x32, mfma 32x32x16 ----------
// R14 = R11 (best measured: conv 296us) with the MFMA shape switched from
// 16x16x32 to 32x32x16.  Same LDS port traffic (8 b128/wave/ktile), same
// accumulator budget (2x2 frags x 16 = 64), but the 32x32 pipe runs at
// 2495 vs 2075 TF (m119) -> 17% fewer MFMA cycles, and 8 instead of 16
// MFMA instructions per ktile.  Fragment row = lane&31, k-chunk = q*2 +
// (lane>>5); rotation swizzle unchanged (bank map stays uniform).
// C/D: col = lane&31, row = (reg&3) + 8*(reg>>2) + 4*(lane>>5)  [verified
// mapping, guide m74/m101] -> epilogue rewritten.

#define STGALL(bi_, tA_, tB_) do { \
    gload16(wpk + (tA_) + aoffg0, &lds[(bi_) * 8192 + ldsa0]); \
    gload16(wpk + (tA_) + aoffg1, &lds[(bi_) * 8192 + ldsa1]); \
    gload16(xt  + (tB_) + boffg,  &lds[24576 + (bi_) * 4096 + ldsb]); \
} while (0)

#define ROWA(mi) (wm * 64 + (mi) * 32 + r32)
#define ROWB(pj) (wp * 64 + (pj) * 32 + r32)
#define POSF(cg_, r_) (((((cg_) + ((r_) >> 1)) & 3)) << 3)
#define LDAF(mi, q) (*(const short8v*)&lds[abase + ROWA(mi) * 32 + POSF((q) * 2 + h2, ROWA(mi))])
#define LDBF(pj, q) (*(const short8v*)&lds[bbase + ROWB(pj) * 32 + POSF((q) * 2 + h2, ROWB(pj))])

#define BARSYNC do { \
    __builtin_amdgcn_s_barrier(); \
    __builtin_amdgcn_sched_barrier(0); \
} while (0)

__global__ __launch_bounds__(512, 4) void conv_mfma(const unsigned short* __restrict__ xt,
                                                    const unsigned short* __restrict__ wpk,
                                                    const float* __restrict__ net_b,
                                                    float* __restrict__ out,
                                                    float* __restrict__ chansum) {
    __shared__ unsigned short lds[36864];  // 72 KB: A ring 3x8192, B ring 3x4096

    const int tid  = threadIdx.x;
    const int lane = tid & 63;
    const int wid  = tid >> 6;         // 0..7
    const int wm   = wid >> 1;         // 0..3  (m quarter, 64 rows)
    const int wp   = wid & 1;          // 0..1  (pixel half, 64 px)
    const int r32  = lane & 31;
    const int h2   = lane >> 5;        // 0..1  (k-half within K=16 chunkpair)

    // XCD-aware bijective swizzle: 1536 = 8 * 192
    const int pb0 = (blockIdx.x & 7) * 192 + (blockIdx.x >> 3);

    // A staging precompute: slot s -> row r = s>>2, pos p = s&3 holds global
    // chunk cg = (p - (r>>1)) & 3; 4 lanes/row cover 64 B contiguous.
    const int cgs = ((tid & 3) - (tid >> 3)) & 3;
    const int aoffg0 = (tid >> 2) * 256 + cgs * 8;   // A rows 0..127
    const int aoffg1 = aoffg0 + 32768;               // A rows 128..255
    const int ldsa0  = tid * 8;
    const int ldsa1  = ldsa0 + 4096;
    const int ldsb   = tid * 8;

    for (int g = pb0; g < 1568; g += 1536) {
        const int p0 = g * 128;

        long boffg;
        {
            int r = tid >> 2;              // pixel row 0..127
            int p = p0 + r;
            int nt = p / HWSZ, hw = p - nt * HWSZ;
            int hh = hw / WW,  w  = hw - hh * WW;
            boffg = ((long)(nt * HP + hh) * WP + w) * 256 + cgs * 8;
        }

        float16v acc[2][2];
        #pragma unroll
        for (int i = 0; i < 2; ++i)
            #pragma unroll
            for (int j = 0; j < 2; ++j) acc[i][j] = (float16v)(0.0f);

        // prologue: stage tiles 0,1 into ring slots 0,1 (kt: rs=kt>>3, co=(kt&7)*32)
        STGALL(0, 0, 0);
        STGALL(1, 32, 32);

        int cur = 0;
        for (int kt = 0; kt < 72; ++kt) {
            const int abase = cur * 8192;
            const int bbase = 24576 + cur * 4096;

            if (kt < 70) {
                const int ktn = kt + 2;
                int nb2 = cur + 2; if (nb2 >= 3) nb2 -= 3;
                const int rsn = ktn >> 3, con = (ktn & 7) * 32;
                const int tAn = rsn * 65536 + con;
                const int tBn = ((rsn / 3) * WP + (rsn - (rsn / 3) * 3)) * 256 + con;
                STGALL(nb2, tAn, tBn);
                asm volatile("s_waitcnt vmcnt(6)" ::: "memory");
            } else if (kt == 70) {
                asm volatile("s_waitcnt vmcnt(3)" ::: "memory");
            } else {
                asm volatile("s_waitcnt vmcnt(0)" ::: "memory");
            }
            BARSYNC;                       // tile kt sealed for all waves

            short8v a00 = LDAF(0, 0), a01 = LDAF(0, 1);
            short8v a10 = LDAF(1, 0), a11 = LDAF(1, 1);
            short8v b00 = LDBF(0, 0), b01 = LDBF(0, 1);
            short8v b10 = LDBF(1, 0), b11 = LDBF(1, 1);

            asm volatile("s_waitcnt lgkmcnt(0)" ::: "memory");
            __builtin_amdgcn_sched_barrier(0);
            __builtin_amdgcn_s_setprio(1);
            acc[0][0] = __builtin_amdgcn_mfma_f32_32x32x16_bf16(a00, b00, acc[0][0], 0, 0, 0);
            acc[0][1] = __builtin_amdgcn_mfma_f32_32x32x16_bf16(a00, b10, acc[0][1], 0, 0, 0);
            acc[1][0] = __builtin_amdgcn_mfma_f32_32x32x16_bf16(a10, b00, acc[1][0], 0, 0, 0);
            acc[1][1] = __builtin_amdgcn_mfma_f32_32x32x16_bf16(a10, b10, acc[1][1], 0, 0, 0);
            acc[0][0] = __builtin_amdgcn_mfma_f32_32x32x16_bf16(a01, b01, acc[0][0], 0, 0, 0);
            acc[0][1] = __builtin_amdgcn_mfma_f32_32x32x16_bf16(a01, b11, acc[0][1], 0, 0, 0);
            acc[1][0] = __builtin_amdgcn_mfma_f32_32x32x16_bf16(a11, b01, acc[1][0], 0, 0, 0);
            acc[1][1] = __builtin_amdgcn_mfma_f32_32x32x16_bf16(a11, b11, acc[1][1], 0, 0, 0);
            __builtin_amdgcn_s_setprio(0);
            BARSYNC;                       // WAR: buffer cur free for restage

            ++cur; if (cur >= 3) cur = 0;
        }

        // epilogue: bias + store + fused channel-sum
        // D layout: col(px) = lane&31, row(m) = (reg&3) + 8*(reg>>2) + 4*h2
        const int pw = p0 + wp * 64;   // 64-aligned -> whole wave-chunk same image
        const int ntw = pw / HWSZ;
        const int hwb = pw - ntw * HWSZ;
        #pragma unroll
        for (int mi = 0; mi < 2; ++mi) {
            #pragma unroll
            for (int reg = 0; reg < 16; ++reg) {
                const int m = wm * 64 + mi * 32 + (reg & 3) + 8 * (reg >> 2) + 4 * h2;
                const float bias = net_b[m];
                float csum = 0.f;
                float* orow = out + ((size_t)ntw * CCH + m) * HWSZ + hwb;
                #pragma unroll
                for (int pj = 0; pj < 2; ++pj) {
                    float v = acc[mi][pj][reg] + bias;
                    orow[pj * 32 + r32] = v;
                    csum += v;
                }
                csum += __shfl_xor(csum, 1);
                csum += __shfl_xor(csum, 2);
                csum += __shfl_xor(csum, 4);
                csum += __shfl_xor(csum, 8);
                csum += __shfl_xor(csum, 16);
                if (r32 == 0) atomicAdd(&chansum[ntw * CCH + m], csum);
            }
        }
    }
}

// ---------------- K2: x_g -> lam 1x1 conv -> xg2[n][c] --------------------
__global__ __launch_bounds__(256) void k2_xg(const float* __restrict__ chansum,
                                             const float* __restrict__ lam_w,
                                             const float* __restrict__ lam_b,
                                             float* __restrict__ xg2) {
    int n = blockIdx.x, c = threadIdx.x;
    __shared__ float xs[256];
    float s = 0.f;
    #pragma unroll
    for (int t = 0; t < 8; ++t) s += chansum[(n * 8 + t) * CCH + c];
    xs[c] = s * (1.0f / (3136.f * 8.f));
    __syncthreads();
    float d = lam_b[c];
    const float* row = lam_w + c * 256;
    for (int cc = 0; cc < 256; ++cc) d += row[cc] * xs[cc];
    xg2[n * 256 + c] = d;
}

// ---------------- K3: MLP+BN+softmax weights, m[n][c][t] ------------------
__global__ __launch_bounds__(256) void k3_wgt(const float* __restrict__ chansum,
                                              const float* __restrict__ xg2,
                                              const float* __restrict__ w1,
                                              const float* __restrict__ bg,
                                              const float* __restrict__ bb,
                                              const float* __restrict__ bm,
                                              const float* __restrict__ bv,
                                              const float* __restrict__ w2,
                                              float* __restrict__ wgt,
                                              float* __restrict__ mbuf) {
    int idx = blockIdx.x * 256 + threadIdx.x;    // n*256+c, 2048
    int n = idx >> 8, c = idx & 255;
    float xg = xg2[idx];
    float p[8];
    #pragma unroll
    for (int t = 0; t < 8; ++t)
        p[t] = chansum[(n * 8 + t) * CCH + c] * (1.0f / 3136.f) + xg;
    float hd[16];
    #pragma unroll
    for (int j = 0; j < 16; ++j) {
        float s = 0.f;
        #pragma unroll
        for (int t = 0; t < 8; ++t) s += p[t] * w1[j * 8 + t];
        s = (s - bm[j]) * (bg[j] * rsqrtf(bv[j] + 1e-5f)) + bb[j];
        hd[j] = fmaxf(s, 0.f);
    }
    float lg[3];
    #pragma unroll
    for (int k = 0; k < 3; ++k) {
        float s = 0.f;
        #pragma unroll
        for (int j = 0; j < 16; ++j) s += hd[j] * w2[k * 16 + j];
        lg[k] = s;
    }
    float mx = fmaxf(fmaxf(lg[0], lg[1]), lg[2]);
    float e0 = expf(lg[0] - mx), e1 = expf(lg[1] - mx), e2 = expf(lg[2] - mx);
    float inv = 1.f / (e0 + e1 + e2);
    float wk[3] = {e0 * inv, e1 * inv, e2 * inv};
    #pragma unroll
    for (int k = 0; k < 3; ++k) wgt[idx * 3 + k] = wk[k];
    #pragma unroll
    for (int t = 0; t < 8; ++t) {
        float s = 0.f;
        #pragma unroll
        for (int k = 0; k < 3; ++k) {
            int tt = t + k - 1;
            if (tt >= 0 && tt < 8) s += wk[k] * p[tt];
        }
        mbuf[idx * 8 + t] = s;
    }
}

// ---------------- K4: ME gate[nt][c] --------------------------------------
__global__ __launch_bounds__(256) void k4_gate(const float* __restrict__ mbuf,
                                               const float* __restrict__ me_w,
                                               float* __restrict__ gate) {
    int b = blockIdx.x;          // n*8+t
    int n = b >> 3, t = b & 7;
    int c = threadIdx.x;
    __shared__ float y[256];
    float yv = 0.f;
    if (t < 7) yv = mbuf[(n * 256 + c) * 8 + t + 1] - mbuf[(n * 256 + c) * 8 + t];
    y[c] = yv;
    __syncthreads();
    float yc = me_w[1] * yv;
    if (c > 0)   yc += me_w[0] * y[c - 1];
    if (c < 255) yc += me_w[2] * y[c + 1];
    gate[b * 256 + c] = 1.f / (1.f + expf(-yc));
}

// ---------------- K5: temporal mix + gate, in-place on d_out --------------
__global__ __launch_bounds__(256) void k5_final(float* __restrict__ out,
                                                const float* __restrict__ wgt,
                                                const float* __restrict__ xg2,
                                                const float* __restrict__ gate) {
    int tid = blockIdx.x * 256 + threadIdx.x;   // 2048 * 784
    int hw4 = tid % 784;
    int nc = tid / 784;
    int n = nc >> 8, c = nc & 255;
    float w0 = wgt[nc * 3 + 0], w1 = wgt[nc * 3 + 1], w2 = wgt[nc * 3 + 2];
    float xg = xg2[nc];
    const size_t tstride = (size_t)CCH * HWSZ;
    size_t base = ((size_t)(n * 8) * CCH + c) * HWSZ + hw4 * 4;

    float4v o[8];
    #pragma unroll
    for (int t = 0; t < 8; ++t) o[t] = *(const float4v*)(out + base + t * tstride);

    #pragma unroll
    for (int t = 0; t < 8; ++t) {
        float g = gate[(n * 8 + t) * CCH + c];
        float4v lam;
        #pragma unroll
        for (int q = 0; q < 4; ++q) {
            float v = w1 * (o[t][q] + xg);
            if (t > 0) v += w0 * (o[t - 1][q] + xg);
            if (t < 7) v += w2 * (o[t + 1][q] + xg);
            lam[q] = g * v;
        }
        *(float4v*)(out + base + t * tstride) = lam;
    }
}

extern "C" void kernel_launch(void* const* d_in, const int* in_sizes, int n_in,
                              void* d_out, int out_size, void* d_ws, size_t ws_size,
                              hipStream_t stream) {
    const float* x      = (const float*)d_in[0];
    const float* net_w  = (const float*)d_in[1];
    const float* net_b  = (const float*)d_in[2];
    const float* lam_w  = (const float*)d_in[3];
    const float* lam_b  = (const float*)d_in[4];
    const float* mlp_w1 = (const float*)d_in[5];
    const float* bn_g   = (const float*)d_in[6];
    const float* bn_b   = (const float*)d_in[7];
    const float* bn_m   = (const float*)d_in[8];
    const float* bn_v   = (const float*)d_in[9];
    const float* mlp_w2 = (const float*)d_in[10];
    const float* me_w   = (const float*)d_in[11];
    float* out = (float*)d_out;

    char* ws = (char*)d_ws;
    unsigned short* xt  = (unsigned short*)(ws + OFF_XT);
    unsigned short* wpk = (unsigned short*)(ws + OFF_WPK);
    float* chansum = (float*)(ws + OFF_CS);
    float* xg2     = (float*)(ws + OFF_XG2);
    float* wgt     = (float*)(ws + OFF_WGT);
    float* mbuf    = (float*)(ws + OFF_M);
    float* gate    = (float*)(ws + OFF_GATE);

    hipMemsetAsync(chansum, 0, SZ_CS, stream);
    kw_pack<<<2304, 256, 0, stream>>>(net_w, wpk);
    k0_transpose<<<64 * 56 * 4, 256, 0, stream>>>(x, xt);
    conv_mfma<<<1536, 512, 0, stream>>>(xt, wpk, net_b, out, chansum);
    k2_xg<<<8, 256, 0, stream>>>(chansum, lam_w, lam_b, xg2);
    k3_wgt<<<8, 256, 0, stream>>>(chansum, xg2, mlp_w1, bn_g, bn_b, bn_m, bn_v, mlp_w2, wgt, mbuf);
    k4_gate<<<64, 256, 0, stream>>>(mbuf, me_w, gate);
    k5_final<<<6272, 256, 0, stream>>>(out, wgt, xg2, gate);
}

// Round 15
// 412.539 us; speedup vs baseline: 1.3252x; 1.1795x over previous
//
#include <hip/hip_runtime.h>
#include <hip/hip_bf16.h>
#include <stdint.h>

#define AS1 __attribute__((address_space(1)))
#define AS3 __attribute__((address_space(3)))

typedef __attribute__((ext_vector_type(8))) short short8v;
typedef __attribute__((ext_vector_type(4))) unsigned short ushort4v;
typedef __attribute__((ext_vector_type(4))) float float4v;

#define NT 64
#define CCH 256
#define HH 56
#define WW 56
#define HWSZ 3136
#define HP 58
#define WP 58

// workspace layout (bytes)
#define OFF_XT   0ull
#define SZ_XT    110231552ull          // 64*58*58*256*2  (bf16 NHWC padded)
#define OFF_WPK  (OFF_XT + SZ_XT)
#define SZ_WPK   1179648ull            // 9*256*256*2
#define OFF_CS   (OFF_WPK + SZ_WPK)
#define SZ_CS    65536ull              // 64*256 f32 channel sums
#define OFF_XG2  (OFF_CS + SZ_CS)
#define SZ_XG2   8192ull               // 8*256 f32
#define OFF_WGT  (OFF_XG2 + SZ_XG2)
#define SZ_WGT   24576ull              // 8*256*3 f32
#define OFF_GATE (OFF_WGT + SZ_WGT)
#define SZ_GATE  65536ull              // 64*256 f32
#define OFF_CVT  (OFF_GATE + SZ_GATE)
#define SZ_CVT   102760448ull          // 200704*256 bf16 conv output

__device__ __forceinline__ unsigned short f2bf(float f) {
    unsigned int u = __float_as_uint(f);
    unsigned int r = (u + 0x7fffu + ((u >> 16) & 1u)) >> 16;
    return (unsigned short)r;
}
__device__ __forceinline__ float bf2f(unsigned short u) {
    return __uint_as_float(((unsigned int)u) << 16);
}

__device__ __forceinline__ void gload16(const unsigned short* g, unsigned short* l) {
    __builtin_amdgcn_global_load_lds((const AS1 void*)g, (AS3 void*)l, 16, 0, 0);
}

// ---------------- K0: NCHW f32 -> NHWC-padded bf16 (with zero borders) ----
__global__ __launch_bounds__(256) void k0_transpose(const float* __restrict__ x,
                                                    unsigned short* __restrict__ xt) {
    int b = blockIdx.x;              // (nt, h, cb) : 64*56*4
    int cb = b & 3;
    int h  = (b >> 2) % 56;
    int nt = b / (4 * 56);
    int c0 = cb * 64;
    int tid = threadIdx.x;

    __shared__ float xs[64 * 57];    // padded stride 57 to dodge bank conflicts

    const float* src = x + ((size_t)nt * CCH + c0) * HWSZ + h * WW;
    for (int li = tid; li < 896; li += 256) {       // 64 rows * 14 float4
        int row = li / 14, f4 = li % 14;
        float4v v = *(const float4v*)(src + (size_t)row * HWSZ + f4 * 4);
        float* d = &xs[row * 57 + f4 * 4];
        d[0] = v.x; d[1] = v.y; d[2] = v.z; d[3] = v.w;
    }
    __syncthreads();

    unsigned short* dst = xt + (((size_t)nt * HP + (h + 1)) * WP) * CCH + c0;
    for (int job = tid; job < 464; job += 256) {    // 58 ww * 8 cgroups
        int ww = job >> 3, cg = job & 7;
        short8v v;
        if (ww == 0 || ww == 57) {
            v = (short8v){0,0,0,0,0,0,0,0};
        } else {
            #pragma unroll
            for (int jj = 0; jj < 8; ++jj)
                v[jj] = (short)f2bf(xs[(cg * 8 + jj) * 57 + (ww - 1)]);
        }
        *(short8v*)(dst + ww * CCH + cg * 8) = v;
    }
    if (h == 0) {   // zero rows hh=0 and hh=57
        unsigned short* d0  = xt + ((size_t)nt * HP + 0)  * WP * CCH + c0;
        unsigned short* d57 = xt + ((size_t)nt * HP + 57) * WP * CCH + c0;
        short8v z = (short8v){0,0,0,0,0,0,0,0};
        for (int job = tid; job < 464; job += 256) {
            int ww = job >> 3, cg = job & 7;
            *(short8v*)(d0  + ww * CCH + cg * 8) = z;
            *(short8v*)(d57 + ww * CCH + cg * 8) = z;
        }
    }
}

// ---------------- KW: pack conv weights -> [rs][k][c] bf16 ----------------
__global__ __launch_bounds__(256) void kw_pack(const float* __restrict__ nw,
                                               unsigned short* __restrict__ wpk) {
    int idx = blockIdx.x * 256 + threadIdx.x;       // 9*256*256 = 589824
    int rs = idx >> 16;
    int k  = (idx >> 8) & 255;
    int c  = idx & 255;
    wpk[idx] = f2bf(nw[(k * 256 + c) * 9 + rs]);
}

// ---------------- conv: implicit GEMM, 256x128x32 (R11 structure) ---------
// Best measured structure (conv 296us): 8 waves of 64x64 (acc 4x4, ~64 VGPR
// -> 4 waves/SIMD from 2 anti-phased blocks), coalesced staging, rotation
// swizzle (2-way = free), 3-ring depth-2 prefetch vmcnt(6), grid 1536+fold.
// OB=1: epilogue stores bf16 into cvt (halves conv write + k5 read traffic);
// OB=0 fallback stores f32 into out (if ws too small for cvt).

#define STGALL(bi_, tA_, tB_) do { \
    gload16(wpk + (tA_) + aoffg0, &lds[(bi_) * 8192 + ldsa0]); \
    gload16(wpk + (tA_) + aoffg1, &lds[(bi_) * 8192 + ldsa1]); \
    gload16(xt  + (tB_) + boffg,  &lds[24576 + (bi_) * 4096 + ldsb]); \
} while (0)

#define LDAF(mi) (*(const short8v*)&lds[abase + (wm * 64 + (mi) * 16 + r16) * 32 + pA * 8])
#define LDBF(j)  (*(const short8v*)&lds[bbase + (wp * 64 + (j) * 16 + r16) * 32 + pA * 8])

#define BARSYNC do { \
    __builtin_amdgcn_s_barrier(); \
    __builtin_amdgcn_sched_barrier(0); \
} while (0)

template <int OB>
__global__ __launch_bounds__(512, 4) void conv_mfma(const unsigned short* __restrict__ xt,
                                                    const unsigned short* __restrict__ wpk,
                                                    const float* __restrict__ net_b,
                                                    float* __restrict__ out,
                                                    unsigned short* __restrict__ cvt,
                                                    float* __restrict__ chansum) {
    __shared__ unsigned short lds[36864];  // 72 KB: A ring 3x8192, B ring 3x4096

    const int tid  = threadIdx.x;
    const int lane = tid & 63;
    const int wid  = tid >> 6;         // 0..7
    const int wm   = wid >> 1;         // 0..3  (m quarter, 64 rows)
    const int wp   = wid & 1;          // 0..1  (pixel half, 64 px)
    const int r16  = lane & 15;
    const int hi   = lane >> 4;        // 0..3  (k-chunk)
    const int pA   = (hi + (r16 >> 1)) & 3;   // rotation-swizzle read position

    // XCD-aware bijective swizzle: 1536 = 8 * 192
    const int pb0 = (blockIdx.x & 7) * 192 + (blockIdx.x >> 3);

    // A staging precompute: slot s -> row r = s>>2, pos p = s&3 holds global
    // chunk cg = (p - (r>>1)) & 3; 4 lanes/row cover 64 B contiguous.
    const int cgs = ((tid & 3) - (tid >> 3)) & 3;
    const int aoffg0 = (tid >> 2) * 256 + cgs * 8;   // A rows 0..127
    const int aoffg1 = aoffg0 + 32768;               // A rows 128..255
    const int ldsa0  = tid * 8;
    const int ldsa1  = ldsa0 + 4096;
    const int ldsb   = tid * 8;

    for (int g = pb0; g < 1568; g += 1536) {
        const int p0 = g * 128;

        long boffg;
        {
            int r = tid >> 2;              // pixel row 0..127
            int p = p0 + r;
            int nt = p / HWSZ, hw = p - nt * HWSZ;
            int hh = hw / WW,  w  = hw - hh * WW;
            boffg = ((long)(nt * HP + hh) * WP + w) * 256 + cgs * 8;
        }

        float4v acc[4][4];
        #pragma unroll
        for (int i = 0; i < 4; ++i)
            #pragma unroll
            for (int j = 0; j < 4; ++j) acc[i][j] = (float4v){0.f, 0.f, 0.f, 0.f};

        // prologue: stage tiles 0,1 into ring slots 0,1 (kt: rs=kt>>3, co=(kt&7)*32)
        STGALL(0, 0, 0);
        STGALL(1, 32, 32);

        int cur = 0;
        for (int kt = 0; kt < 72; ++kt) {
            const int abase = cur * 8192;
            const int bbase = 24576 + cur * 4096;

            if (kt < 70) {
                const int ktn = kt + 2;
                int nb2 = cur + 2; if (nb2 >= 3) nb2 -= 3;
                const int rsn = ktn >> 3, con = (ktn & 7) * 32;
                const int tAn = rsn * 65536 + con;
                const int tBn = ((rsn / 3) * WP + (rsn - (rsn / 3) * 3)) * 256 + con;
                STGALL(nb2, tAn, tBn);
                asm volatile("s_waitcnt vmcnt(6)" ::: "memory");
            } else if (kt == 70) {
                asm volatile("s_waitcnt vmcnt(3)" ::: "memory");
            } else {
                asm volatile("s_waitcnt vmcnt(0)" ::: "memory");
            }
            BARSYNC;                       // tile kt sealed for all waves

            short8v afrag[4], bfrag[4];
            #pragma unroll
            for (int mi = 0; mi < 4; ++mi) afrag[mi] = LDAF(mi);
            #pragma unroll
            for (int j = 0; j < 4; ++j) bfrag[j] = LDBF(j);

            asm volatile("s_waitcnt lgkmcnt(0)" ::: "memory");
            __builtin_amdgcn_sched_barrier(0);
            __builtin_amdgcn_s_setprio(1);
            #pragma unroll
            for (int j = 0; j < 4; ++j)
                #pragma unroll
                for (int mi = 0; mi < 4; ++mi)
                    acc[mi][j] = __builtin_amdgcn_mfma_f32_16x16x32_bf16(afrag[mi], bfrag[j], acc[mi][j], 0, 0, 0);
            __builtin_amdgcn_s_setprio(0);
            BARSYNC;                       // WAR: buffer cur free for restage

            ++cur; if (cur >= 3) cur = 0;
        }

        // epilogue: bias + store + fused channel-sum
        const int pw = p0 + wp * 64;   // 64-aligned -> whole wave-chunk same image
        const int ntw = pw / HWSZ;
        const int hwb = pw - ntw * HWSZ;
        #pragma unroll
        for (int mi = 0; mi < 4; ++mi) {
            #pragma unroll
            for (int r = 0; r < 4; ++r) {
                const int m = wm * 64 + mi * 16 + hi * 4 + r;
                const float bias = net_b[m];
                float csum = 0.f;
                const size_t obase = ((size_t)ntw * CCH + m) * HWSZ + hwb;
                #pragma unroll
                for (int j = 0; j < 4; ++j) {
                    float v = acc[mi][j][r] + bias;
                    if (OB) cvt[obase + j * 16 + r16] = f2bf(v);
                    else    out[obase + j * 16 + r16] = v;
                    csum += v;
                }
                csum += __shfl_xor(csum, 1);
                csum += __shfl_xor(csum, 2);
                csum += __shfl_xor(csum, 4);
                csum += __shfl_xor(csum, 8);
                if (r16 == 0) atomicAdd(&chansum[ntw * CCH + m], csum);
            }
        }
    }
}

// ---------------- K234: fused x_g -> MLP/BN/softmax -> ME gate ------------
__global__ __launch_bounds__(256) void k234(const float* __restrict__ chansum,
                                            const float* __restrict__ lam_w,
                                            const float* __restrict__ lam_b,
                                            const float* __restrict__ mw1,
                                            const float* __restrict__ bg,
                                            const float* __restrict__ bb,
                                            const float* __restrict__ bm,
                                            const float* __restrict__ bv,
                                            const float* __restrict__ mw2,
                                            const float* __restrict__ me_w,
                                            float* __restrict__ xg2,
                                            float* __restrict__ wgt,
                                            float* __restrict__ gate) {
    int n = blockIdx.x, c = threadIdx.x;
    __shared__ float xs[256];
    __shared__ float yd[8][256];

    float s = 0.f;
    #pragma unroll
    for (int t = 0; t < 8; ++t) s += chansum[(n * 8 + t) * CCH + c];
    xs[c] = s * (1.0f / (3136.f * 8.f));
    __syncthreads();

    float xg = lam_b[c];
    const float* row = lam_w + c * 256;
    for (int cc = 0; cc < 256; ++cc) xg += row[cc] * xs[cc];
    xg2[n * 256 + c] = xg;

    float p[8];
    #pragma unroll
    for (int t = 0; t < 8; ++t)
        p[t] = chansum[(n * 8 + t) * CCH + c] * (1.0f / 3136.f) + xg;

    float hd[16];
    #pragma unroll
    for (int j = 0; j < 16; ++j) {
        float v = 0.f;
        #pragma unroll
        for (int t = 0; t < 8; ++t) v += p[t] * mw1[j * 8 + t];
        v = (v - bm[j]) * (bg[j] * rsqrtf(bv[j] + 1e-5f)) + bb[j];
        hd[j] = fmaxf(v, 0.f);
    }
    float lg[3];
    #pragma unroll
    for (int k = 0; k < 3; ++k) {
        float v = 0.f;
        #pragma unroll
        for (int j = 0; j < 16; ++j) v += hd[j] * mw2[k * 16 + j];
        lg[k] = v;
    }
    float mx = fmaxf(fmaxf(lg[0], lg[1]), lg[2]);
    float e0 = expf(lg[0] - mx), e1 = expf(lg[1] - mx), e2 = expf(lg[2] - mx);
    float inv = 1.f / (e0 + e1 + e2);
    float wk[3] = {e0 * inv, e1 * inv, e2 * inv};
    int idx = n * 256 + c;
    #pragma unroll
    for (int k = 0; k < 3; ++k) wgt[idx * 3 + k] = wk[k];

    float mb[8];
    #pragma unroll
    for (int t = 0; t < 8; ++t) {
        float v = 0.f;
        #pragma unroll
        for (int k = 0; k < 3; ++k) {
            int tt = t + k - 1;
            if (tt >= 0 && tt < 8) v += wk[k] * p[tt];
        }
        mb[t] = v;
    }
    #pragma unroll
    for (int t = 0; t < 7; ++t) yd[t][c] = mb[t + 1] - mb[t];
    yd[7][c] = 0.f;
    __syncthreads();

    float w0 = me_w[0], w1v = me_w[1], w2v = me_w[2];
    #pragma unroll
    for (int t = 0; t < 8; ++t) {
        float yc = w1v * yd[t][c];
        if (c > 0)   yc += w0 * yd[t][c - 1];
        if (c < 255) yc += w2v * yd[t][c + 1];
        gate[(n * 8 + t) * CCH + c] = 1.f / (1.f + expf(-yc));
    }
}

// ---------------- K5: temporal mix + gate -> d_out ------------------------
template <int OB>
__global__ __launch_bounds__(256) void k5_final(float* __restrict__ out,
                                                const unsigned short* __restrict__ cvt,
                                                const float* __restrict__ wgt,
                                                const float* __restrict__ xg2,
                                                const float* __restrict__ gate) {
    int tid = blockIdx.x * 256 + threadIdx.x;   // 2048 * 784
    int hw4 = tid % 784;
    int nc = tid / 784;
    int n = nc >> 8, c = nc & 255;
    float w0 = wgt[nc * 3 + 0], w1 = wgt[nc * 3 + 1], w2 = wgt[nc * 3 + 2];
    float xg = xg2[nc];
    const size_t tstride = (size_t)CCH * HWSZ;
    size_t base = ((size_t)(n * 8) * CCH + c) * HWSZ + hw4 * 4;

    float4v o[8];
    #pragma unroll
    for (int t = 0; t < 8; ++t) {
        if (OB) {
            ushort4v v = *(const ushort4v*)(cvt + base + t * tstride);
            #pragma unroll
            for (int q = 0; q < 4; ++q) o[t][q] = bf2f(v[q]);
        } else {
            o[t] = *(const float4v*)(out + base + t * tstride);
        }
    }

    #pragma unroll
    for (int t = 0; t < 8; ++t) {
        float g = gate[(n * 8 + t) * CCH + c];
        float4v lam;
        #pragma unroll
        for (int q = 0; q < 4; ++q) {
            float v = w1 * (o[t][q] + xg);
            if (t > 0) v += w0 * (o[t - 1][q] + xg);
            if (t < 7) v += w2 * (o[t + 1][q] + xg);
            lam[q] = g * v;
        }
        *(float4v*)(out + base + t * tstride) = lam;
    }
}

extern "C" void kernel_launch(void* const* d_in, const int* in_sizes, int n_in,
                              void* d_out, int out_size, void* d_ws, size_t ws_size,
                              hipStream_t stream) {
    const float* x      = (const float*)d_in[0];
    const float* net_w  = (const float*)d_in[1];
    const float* net_b  = (const float*)d_in[2];
    const float* lam_w  = (const float*)d_in[3];
    const float* lam_b  = (const float*)d_in[4];
    const float* mlp_w1 = (const float*)d_in[5];
    const float* bn_g   = (const float*)d_in[6];
    const float* bn_b   = (const float*)d_in[7];
    const float* bn_m   = (const float*)d_in[8];
    const float* bn_v   = (const float*)d_in[9];
    const float* mlp_w2 = (const float*)d_in[10];
    const float* me_w   = (const float*)d_in[11];
    float* out = (float*)d_out;

    char* ws = (char*)d_ws;
    unsigned short* xt  = (unsigned short*)(ws + OFF_XT);
    unsigned short* wpk = (unsigned short*)(ws + OFF_WPK);
    float* chansum = (float*)(ws + OFF_CS);
    float* xg2     = (float*)(ws + OFF_XG2);
    float* wgt     = (float*)(ws + OFF_WGT);
    float* gate    = (float*)(ws + OFF_GATE);
    unsigned short* cvt = (unsigned short*)(ws + OFF_CVT);

    const bool use_bf16 = (ws_size >= OFF_CVT + SZ_CVT);

    hipMemsetAsync(chansum, 0, SZ_CS, stream);
    kw_pack<<<2304, 256, 0, stream>>>(net_w, wpk);
    k0_transpose<<<64 * 56 * 4, 256, 0, stream>>>(x, xt);
    if (use_bf16)
        conv_mfma<1><<<1536, 512, 0, stream>>>(xt, wpk, net_b, out, cvt, chansum);
    else
        conv_mfma<0><<<1536, 512, 0, stream>>>(xt, wpk, net_b, out, cvt, chansum);
    k234<<<8, 256, 0, stream>>>(chansum, lam_w, lam_b, mlp_w1, bn_g, bn_b, bn_m, bn_v,
                                mlp_w2, me_w, xg2, wgt, gate);
    if (use_bf16)
        k5_final<1><<<6272, 256, 0, stream>>>(out, cvt, wgt, xg2, gate);
    else
        k5_final<0><<<6272, 256, 0, stream>>>(out, cvt, wgt, xg2, gate);
}

// Round 16
// 404.263 us; speedup vs baseline: 1.3523x; 1.0205x over previous
//
#include <hip/hip_runtime.h>
#include <hip/hip_bf16.h>
#include <stdint.h>

#define AS1 __attribute__((address_space(1)))
#define AS3 __attribute__((address_space(3)))

typedef __attribute__((ext_vector_type(8))) short short8v;
typedef __attribute__((ext_vector_type(4))) unsigned short ushort4v;
typedef __attribute__((ext_vector_type(4))) float float4v;

#define NT 64
#define CCH 256
#define HH 56
#define WW 56
#define HWSZ 3136
#define HP 58
#define WP 58
#define TAILP 196608    // first tail pixel (tiles 1536..1567)

// workspace layout (bytes)
#define OFF_XT   0ull
#define SZ_XT    110231552ull          // 64*58*58*256*2  (bf16 NHWC padded)
#define OFF_WPK  (OFF_XT + SZ_XT)
#define SZ_WPK   1179648ull            // 9*256*256*2
#define OFF_CS   (OFF_WPK + SZ_WPK)
#define SZ_CS    65536ull              // 64*256 f32 channel sums
#define OFF_XG2  (OFF_CS + SZ_CS)
#define SZ_XG2   8192ull               // 8*256 f32
#define OFF_WGT  (OFF_XG2 + SZ_XG2)
#define SZ_WGT   24576ull              // 8*256*3 f32
#define OFF_GATE (OFF_WGT + SZ_WGT)
#define SZ_GATE  65536ull              // 64*256 f32
#define OFF_CVT  (OFF_GATE + SZ_GATE)
#define SZ_CVT   102760448ull          // 200704*256 bf16 conv output

__device__ __forceinline__ unsigned short f2bf(float f) {
    unsigned int u = __float_as_uint(f);
    unsigned int r = (u + 0x7fffu + ((u >> 16) & 1u)) >> 16;
    return (unsigned short)r;
}
__device__ __forceinline__ float bf2f(unsigned short u) {
    return __uint_as_float(((unsigned int)u) << 16);
}

__device__ __forceinline__ void gload16(const unsigned short* g, unsigned short* l) {
    __builtin_amdgcn_global_load_lds((const AS1 void*)g, (AS3 void*)l, 16, 0, 0);
}

// ---------------- K0: NCHW f32 -> NHWC-padded bf16 (with zero borders) ----
__global__ __launch_bounds__(256) void k0_transpose(const float* __restrict__ x,
                                                    unsigned short* __restrict__ xt) {
    int b = blockIdx.x;              // (nt, h, cb) : 64*56*4
    int cb = b & 3;
    int h  = (b >> 2) % 56;
    int nt = b / (4 * 56);
    int c0 = cb * 64;
    int tid = threadIdx.x;

    __shared__ float xs[64 * 57];    // padded stride 57 to dodge bank conflicts

    const float* src = x + ((size_t)nt * CCH + c0) * HWSZ + h * WW;
    for (int li = tid; li < 896; li += 256) {       // 64 rows * 14 float4
        int row = li / 14, f4 = li % 14;
        float4v v = *(const float4v*)(src + (size_t)row * HWSZ + f4 * 4);
        float* d = &xs[row * 57 + f4 * 4];
        d[0] = v.x; d[1] = v.y; d[2] = v.z; d[3] = v.w;
    }
    __syncthreads();

    unsigned short* dst = xt + (((size_t)nt * HP + (h + 1)) * WP) * CCH + c0;
    for (int job = tid; job < 464; job += 256) {    // 58 ww * 8 cgroups
        int ww = job >> 3, cg = job & 7;
        short8v v;
        if (ww == 0 || ww == 57) {
            v = (short8v){0,0,0,0,0,0,0,0};
        } else {
            #pragma unroll
            for (int jj = 0; jj < 8; ++jj)
                v[jj] = (short)f2bf(xs[(cg * 8 + jj) * 57 + (ww - 1)]);
        }
        *(short8v*)(dst + ww * CCH + cg * 8) = v;
    }
    if (h == 0) {   // zero rows hh=0 and hh=57
        unsigned short* d0  = xt + ((size_t)nt * HP + 0)  * WP * CCH + c0;
        unsigned short* d57 = xt + ((size_t)nt * HP + 57) * WP * CCH + c0;
        short8v z = (short8v){0,0,0,0,0,0,0,0};
        for (int job = tid; job < 464; job += 256) {
            int ww = job >> 3, cg = job & 7;
            *(short8v*)(d0  + ww * CCH + cg * 8) = z;
            *(short8v*)(d57 + ww * CCH + cg * 8) = z;
        }
    }
}

// ---------------- KW: pack conv weights -> [rs][k][c] bf16 ----------------
__global__ __launch_bounds__(256) void kw_pack(const float* __restrict__ nw,
                                               unsigned short* __restrict__ wpk) {
    int idx = blockIdx.x * 256 + threadIdx.x;       // 9*256*256 = 589824
    int rs = idx >> 16;
    int k  = (idx >> 8) & 255;
    int c  = idx & 255;
    wpk[idx] = f2bf(nw[(k * 256 + c) * 9 + rs]);
}

// ---------------- KI: init tail region of out (bias) + chansum bias terms -
// Tail pixels [196608, 200704): images 62 (hw>=2176, 960px) and 63 (all).
__global__ __launch_bounds__(256) void kinit(const float* __restrict__ net_b,
                                             float* __restrict__ out,
                                             float* __restrict__ chansum) {
    int idx = blockIdx.x * 256 + threadIdx.x;    // 1,048,576
    int m  = idx >> 12;          // 0..255
    int pp = idx & 4095;         // 0..4095
    int p  = TAILP + pp;
    int nt = p / HWSZ, hw = p - nt * HWSZ;
    out[((size_t)nt * CCH + m) * HWSZ + hw] = net_b[m];
    if (pp < 512) {              // 2 images x 256 channels
        int img = 62 + (pp >> 8);
        int mm  = pp & 255;
        float npix = (img == 62) ? 960.f : 3136.f;
        chansum[img * CCH + mm] = npix * net_b[mm];
    }
}

// ---------------- conv: implicit GEMM, 256x128x32 (R11 structure) ---------
// Blocks 0..1535: one full tile each (R11 inner loop, best measured).
// Blocks 1536..1599 (dispatched LAST): 2-way split-K halves (36 ktiles) of
// the 32 tail tiles -> round 4 shrinks from T to T/2 (makespan 4T -> 3.5T).
// Tail partials accumulate f32 atomicAdd into out (kinit pre-wrote bias);
// k5 reads tail pixels from out(f32), the rest from cvt(bf16).

#define STGALL(bi_, tA_, tB_) do { \
    gload16(wpk + (tA_) + aoffg0, &lds[(bi_) * 8192 + ldsa0]); \
    gload16(wpk + (tA_) + aoffg1, &lds[(bi_) * 8192 + ldsa1]); \
    gload16(xt  + (tB_) + boffg,  &lds[24576 + (bi_) * 4096 + ldsb]); \
} while (0)

#define LDAF(mi) (*(const short8v*)&lds[abase + (wm * 64 + (mi) * 16 + r16) * 32 + pA * 8])
#define LDBF(j)  (*(const short8v*)&lds[bbase + (wp * 64 + (j) * 16 + r16) * 32 + pA * 8])

#define KTA(kt) ((((kt) >> 3) << 16) + (((kt) & 7) * 32))
#define KTB(kt) (((((kt) >> 3) / 3) * WP + (((kt) >> 3) - (((kt) >> 3) / 3) * 3)) * 256 + (((kt) & 7) * 32))

#define BARSYNC do { \
    __builtin_amdgcn_s_barrier(); \
    __builtin_amdgcn_sched_barrier(0); \
} while (0)

#define KTILE_BODY \
    short8v afrag[4], bfrag[4]; \
    _Pragma("unroll") \
    for (int mi = 0; mi < 4; ++mi) afrag[mi] = LDAF(mi); \
    _Pragma("unroll") \
    for (int j = 0; j < 4; ++j) bfrag[j] = LDBF(j); \
    asm volatile("s_waitcnt lgkmcnt(0)" ::: "memory"); \
    __builtin_amdgcn_sched_barrier(0); \
    __builtin_amdgcn_s_setprio(1); \
    _Pragma("unroll") \
    for (int j = 0; j < 4; ++j) \
        _Pragma("unroll") \
        for (int mi = 0; mi < 4; ++mi) \
            acc[mi][j] = __builtin_amdgcn_mfma_f32_16x16x32_bf16(afrag[mi], bfrag[j], acc[mi][j], 0, 0, 0); \
    __builtin_amdgcn_s_setprio(0); \
    BARSYNC;

template <int OB>
__global__ __launch_bounds__(512, 4) void conv_mfma(const unsigned short* __restrict__ xt,
                                                    const unsigned short* __restrict__ wpk,
                                                    const float* __restrict__ net_b,
                                                    float* __restrict__ out,
                                                    unsigned short* __restrict__ cvt,
                                                    float* __restrict__ chansum) {
    __shared__ unsigned short lds[36864];  // 72 KB: A ring 3x8192, B ring 3x4096

    const int tid  = threadIdx.x;
    const int lane = tid & 63;
    const int wid  = tid >> 6;         // 0..7
    const int wm   = wid >> 1;         // 0..3  (m quarter, 64 rows)
    const int wp   = wid & 1;          // 0..1  (pixel half, 64 px)
    const int r16  = lane & 15;
    const int hi   = lane >> 4;        // 0..3  (k-chunk)
    const int pA   = (hi + (r16 >> 1)) & 3;   // rotation-swizzle read position

    const int bid = blockIdx.x;

    // A staging precompute: slot s -> row r = s>>2, pos p = s&3 holds global
    // chunk cg = (p - (r>>1)) & 3; 4 lanes/row cover 64 B contiguous.
    const int cgs = ((tid & 3) - (tid >> 3)) & 3;
    const int aoffg0 = (tid >> 2) * 256 + cgs * 8;   // A rows 0..127
    const int aoffg1 = aoffg0 + 32768;               // A rows 128..255
    const int ldsa0  = tid * 8;
    const int ldsa1  = ldsa0 + 4096;
    const int ldsb   = tid * 8;

    float4v acc[4][4];
    #pragma unroll
    for (int i = 0; i < 4; ++i)
        #pragma unroll
        for (int j = 0; j < 4; ++j) acc[i][j] = (float4v){0.f, 0.f, 0.f, 0.f};

    if (bid < 1536) {
        // ---------- regular: one full tile ----------
        // XCD-aware bijective swizzle: 1536 = 8 * 192
        const int pb0 = (bid & 7) * 192 + (bid >> 3);
        const int p0 = pb0 * 128;

        long boffg;
        {
            int r = tid >> 2;              // pixel row 0..127
            int p = p0 + r;
            int nt = p / HWSZ, hw = p - nt * HWSZ;
            int hh = hw / WW,  w  = hw - hh * WW;
            boffg = ((long)(nt * HP + hh) * WP + w) * 256 + cgs * 8;
        }

        STGALL(0, 0, 0);
        STGALL(1, 32, 32);

        int cur = 0;
        for (int kt = 0; kt < 72; ++kt) {
            const int abase = cur * 8192;
            const int bbase = 24576 + cur * 4096;

            if (kt < 70) {
                const int ktn = kt + 2;
                int nb2 = cur + 2; if (nb2 >= 3) nb2 -= 3;
                STGALL(nb2, KTA(ktn), KTB(ktn));
                asm volatile("s_waitcnt vmcnt(6)" ::: "memory");
            } else if (kt == 70) {
                asm volatile("s_waitcnt vmcnt(3)" ::: "memory");
            } else {
                asm volatile("s_waitcnt vmcnt(0)" ::: "memory");
            }
            BARSYNC;

            KTILE_BODY
            ++cur; if (cur >= 3) cur = 0;
        }

        // epilogue: bias + store + fused channel-sum
        const int pw = p0 + wp * 64;
        const int ntw = pw / HWSZ;
        const int hwb = pw - ntw * HWSZ;
        #pragma unroll
        for (int mi = 0; mi < 4; ++mi) {
            #pragma unroll
            for (int r = 0; r < 4; ++r) {
                const int m = wm * 64 + mi * 16 + hi * 4 + r;
                const float bias = net_b[m];
                float csum = 0.f;
                const size_t obase = ((size_t)ntw * CCH + m) * HWSZ + hwb;
                #pragma unroll
                for (int j = 0; j < 4; ++j) {
                    float v = acc[mi][j][r] + bias;
                    if (OB) cvt[obase + j * 16 + r16] = f2bf(v);
                    else    out[obase + j * 16 + r16] = v;
                    csum += v;
                }
                csum += __shfl_xor(csum, 1);
                csum += __shfl_xor(csum, 2);
                csum += __shfl_xor(csum, 4);
                csum += __shfl_xor(csum, 8);
                if (r16 == 0) atomicAdd(&chansum[ntw * CCH + m], csum);
            }
        }
    } else {
        // ---------- tail: half-K of one of the 32 tail tiles ----------
        const int tb = bid - 1536;           // 0..63
        const int p0 = (1536 + (tb >> 1)) * 128;
        const int k0 = (tb & 1) * 36;

        long boffg;
        {
            int r = tid >> 2;
            int p = p0 + r;
            int nt = p / HWSZ, hw = p - nt * HWSZ;
            int hh = hw / WW,  w  = hw - hh * WW;
            boffg = ((long)(nt * HP + hh) * WP + w) * 256 + cgs * 8;
        }

        STGALL(0, KTA(k0), KTB(k0));
        STGALL(1, KTA(k0 + 1), KTB(k0 + 1));

        int cur = 0;
        for (int i = 0; i < 36; ++i) {
            const int abase = cur * 8192;
            const int bbase = 24576 + cur * 4096;

            if (i < 34) {
                int nb2 = cur + 2; if (nb2 >= 3) nb2 -= 3;
                const int ktn = k0 + i + 2;
                STGALL(nb2, KTA(ktn), KTB(ktn));
                asm volatile("s_waitcnt vmcnt(6)" ::: "memory");
            } else if (i == 34) {
                asm volatile("s_waitcnt vmcnt(3)" ::: "memory");
            } else {
                asm volatile("s_waitcnt vmcnt(0)" ::: "memory");
            }
            BARSYNC;

            KTILE_BODY
            ++cur; if (cur >= 3) cur = 0;
        }

        // tail epilogue: atomic accumulate into f32 out (no bias), csum
        const int pw = p0 + wp * 64;
        const int ntw = pw / HWSZ;
        const int hwb = pw - ntw * HWSZ;
        #pragma unroll
        for (int mi = 0; mi < 4; ++mi) {
            #pragma unroll
            for (int r = 0; r < 4; ++r) {
                const int m = wm * 64 + mi * 16 + hi * 4 + r;
                float csum = 0.f;
                float* orow = out + ((size_t)ntw * CCH + m) * HWSZ + hwb;
                #pragma unroll
                for (int j = 0; j < 4; ++j) {
                    float v = acc[mi][j][r];
                    atomicAdd(&orow[j * 16 + r16], v);
                    csum += v;
                }
                csum += __shfl_xor(csum, 1);
                csum += __shfl_xor(csum, 2);
                csum += __shfl_xor(csum, 4);
                csum += __shfl_xor(csum, 8);
                if (r16 == 0) atomicAdd(&chansum[ntw * CCH + m], csum);
            }
        }
    }
}

// ---------------- K234: fused x_g -> MLP/BN/softmax -> ME gate ------------
__global__ __launch_bounds__(256) void k234(const float* __restrict__ chansum,
                                            const float* __restrict__ lam_w,
                                            const float* __restrict__ lam_b,
                                            const float* __restrict__ mw1,
                                            const float* __restrict__ bg,
                                            const float* __restrict__ bb,
                                            const float* __restrict__ bm,
                                            const float* __restrict__ bv,
                                            const float* __restrict__ mw2,
                                            const float* __restrict__ me_w,
                                            float* __restrict__ xg2,
                                            float* __restrict__ wgt,
                                            float* __restrict__ gate) {
    int n = blockIdx.x, c = threadIdx.x;
    __shared__ float xs[256];
    __shared__ float yd[8][256];

    float s = 0.f;
    #pragma unroll
    for (int t = 0; t < 8; ++t) s += chansum[(n * 8 + t) * CCH + c];
    xs[c] = s * (1.0f / (3136.f * 8.f));
    __syncthreads();

    float xg = lam_b[c];
    const float* row = lam_w + c * 256;
    for (int cc = 0; cc < 256; ++cc) xg += row[cc] * xs[cc];
    xg2[n * 256 + c] = xg;

    float p[8];
    #pragma unroll
    for (int t = 0; t < 8; ++t)
        p[t] = chansum[(n * 8 + t) * CCH + c] * (1.0f / 3136.f) + xg;

    float hd[16];
    #pragma unroll
    for (int j = 0; j < 16; ++j) {
        float v = 0.f;
        #pragma unroll
        for (int t = 0; t < 8; ++t) v += p[t] * mw1[j * 8 + t];
        v = (v - bm[j]) * (bg[j] * rsqrtf(bv[j] + 1e-5f)) + bb[j];
        hd[j] = fmaxf(v, 0.f);
    }
    float lg[3];
    #pragma unroll
    for (int k = 0; k < 3; ++k) {
        float v = 0.f;
        #pragma unroll
        for (int j = 0; j < 16; ++j) v += hd[j] * mw2[k * 16 + j];
        lg[k] = v;
    }
    float mx = fmaxf(fmaxf(lg[0], lg[1]), lg[2]);
    float e0 = expf(lg[0] - mx), e1 = expf(lg[1] - mx), e2 = expf(lg[2] - mx);
    float inv = 1.f / (e0 + e1 + e2);
    float wk[3] = {e0 * inv, e1 * inv, e2 * inv};
    int idx = n * 256 + c;
    #pragma unroll
    for (int k = 0; k < 3; ++k) wgt[idx * 3 + k] = wk[k];

    float mb[8];
    #pragma unroll
    for (int t = 0; t < 8; ++t) {
        float v = 0.f;
        #pragma unroll
        for (int k = 0; k < 3; ++k) {
            int tt = t + k - 1;
            if (tt >= 0 && tt < 8) v += wk[k] * p[tt];
        }
        mb[t] = v;
    }
    #pragma unroll
    for (int t = 0; t < 7; ++t) yd[t][c] = mb[t + 1] - mb[t];
    yd[7][c] = 0.f;
    __syncthreads();

    float w0 = me_w[0], w1v = me_w[1], w2v = me_w[2];
    #pragma unroll
    for (int t = 0; t < 8; ++t) {
        float yc = w1v * yd[t][c];
        if (c > 0)   yc += w0 * yd[t][c - 1];
        if (c < 255) yc += w2v * yd[t][c + 1];
        gate[(n * 8 + t) * CCH + c] = 1.f / (1.f + expf(-yc));
    }
}

// ---------------- K5: temporal mix + gate -> d_out ------------------------
template <int OB>
__global__ __launch_bounds__(256) void k5_final(float* __restrict__ out,
                                                const unsigned short* __restrict__ cvt,
                                                const float* __restrict__ wgt,
                                                const float* __restrict__ xg2,
                                                const float* __restrict__ gate) {
    int tid = blockIdx.x * 256 + threadIdx.x;   // 2048 * 784
    int hw4 = tid % 784;
    int nc = tid / 784;
    int n = nc >> 8, c = nc & 255;
    float w0 = wgt[nc * 3 + 0], w1 = wgt[nc * 3 + 1], w2 = wgt[nc * 3 + 2];
    float xg = xg2[nc];
    const size_t tstride = (size_t)CCH * HWSZ;
    size_t base = ((size_t)(n * 8) * CCH + c) * HWSZ + hw4 * 4;

    float4v o[8];
    #pragma unroll
    for (int t = 0; t < 8; ++t) {
        size_t addr = base + t * tstride;
        if (OB) {
            int p = (n * 8 + t) * HWSZ + hw4 * 4;   // global pixel index
            if (p >= TAILP) {                        // tail: f32 in out
                o[t] = *(const float4v*)(out + addr);
            } else {
                ushort4v v = *(const ushort4v*)(cvt + addr);
                #pragma unroll
                for (int q = 0; q < 4; ++q) o[t][q] = bf2f(v[q]);
            }
        } else {
            o[t] = *(const float4v*)(out + addr);
        }
    }

    #pragma unroll
    for (int t = 0; t < 8; ++t) {
        float g = gate[(n * 8 + t) * CCH + c];
        float4v lam;
        #pragma unroll
        for (int q = 0; q < 4; ++q) {
            float v = w1 * (o[t][q] + xg);
            if (t > 0) v += w0 * (o[t - 1][q] + xg);
            if (t < 7) v += w2 * (o[t + 1][q] + xg);
            lam[q] = g * v;
        }
        *(float4v*)(out + base + t * tstride) = lam;
    }
}

extern "C" void kernel_launch(void* const* d_in, const int* in_sizes, int n_in,
                              void* d_out, int out_size, void* d_ws, size_t ws_size,
                              hipStream_t stream) {
    const float* x      = (const float*)d_in[0];
    const float* net_w  = (const float*)d_in[1];
    const float* net_b  = (const float*)d_in[2];
    const float* lam_w  = (const float*)d_in[3];
    const float* lam_b  = (const float*)d_in[4];
    const float* mlp_w1 = (const float*)d_in[5];
    const float* bn_g   = (const float*)d_in[6];
    const float* bn_b   = (const float*)d_in[7];
    const float* bn_m   = (const float*)d_in[8];
    const float* bn_v   = (const float*)d_in[9];
    const float* mlp_w2 = (const float*)d_in[10];
    const float* me_w   = (const float*)d_in[11];
    float* out = (float*)d_out;

    char* ws = (char*)d_ws;
    unsigned short* xt  = (unsigned short*)(ws + OFF_XT);
    unsigned short* wpk = (unsigned short*)(ws + OFF_WPK);
    float* chansum = (float*)(ws + OFF_CS);
    float* xg2     = (float*)(ws + OFF_XG2);
    float* wgt     = (float*)(ws + OFF_WGT);
    float* gate    = (float*)(ws + OFF_GATE);
    unsigned short* cvt = (unsigned short*)(ws + OFF_CVT);

    const bool use_bf16 = (ws_size >= OFF_CVT + SZ_CVT);

    hipMemsetAsync(chansum, 0, SZ_CS, stream);
    kw_pack<<<2304, 256, 0, stream>>>(net_w, wpk);
    kinit<<<4096, 256, 0, stream>>>(net_b, out, chansum);
    k0_transpose<<<64 * 56 * 4, 256, 0, stream>>>(x, xt);
    if (use_bf16)
        conv_mfma<1><<<1600, 512, 0, stream>>>(xt, wpk, net_b, out, cvt, chansum);
    else
        conv_mfma<0><<<1600, 512, 0, stream>>>(xt, wpk, net_b, out, cvt, chansum);
    k234<<<8, 256, 0, stream>>>(chansum, lam_w, lam_b, mlp_w1, bn_g, bn_b, bn_m, bn_v,
                                mlp_w2, me_w, xg2, wgt, gate);
    if (use_bf16)
        k5_final<1><<<6272, 256, 0, stream>>>(out, cvt, wgt, xg2, gate);
    else
        k5_final<0><<<6272, 256, 0, stream>>>(out, cvt, wgt, xg2, gate);
}